// Round 3
// baseline (165.072 us; speedup 1.0000x reference)
//
#include <hip/hip_runtime.h>
#include <hip/hip_bf16.h>

#define BB 2048
#define AA 96
#define NIN 128
#define NHID 64

typedef __attribute__((ext_vector_type(8))) short bf16x8;
typedef __attribute__((ext_vector_type(4))) float f32x4;

static __device__ __forceinline__ unsigned cvt_pk_hw(float a, float b) {
    __hip_bfloat162 h = __float22bfloat162_rn(make_float2(a, b));
    unsigned u; __builtin_memcpy(&u, &h, 4);   // memcpy: no triviality requirement
    return u;
}

// per-tile epilogue: softplus + dot(w2), xor-reduce within quad; returns the
// per-atom value selected for lanes nl&3. All indexing compile-time (rule #20).
static __device__ __forceinline__ float tile_reduce(const f32x4* acc,
                                                    const float* b1v,
                                                    const float* w2v,
                                                    int nl) {
    const float LOG2E = 1.4426950408889634f;
    const float LN2   = 0.6931471805599453f;
    float v[4];
    #pragma unroll
    for (int r = 0; r < 4; ++r) {
        float p = 0.f;
        #pragma unroll
        for (int t = 0; t < 4; ++t) {
            float x  = acc[t][r] + b1v[t];
            float ax = fabsf(x);
            float em = exp2f(-ax * LOG2E);
            float sp = fmaxf(x, 0.f) + log2f(1.f + em) * LN2;
            p = fmaf(sp - LN2, w2v[t], p);
        }
        p += __shfl_xor(p, 1); p += __shfl_xor(p, 2);
        p += __shfl_xor(p, 4); p += __shfl_xor(p, 8);
        v[r] = p;
    }
    const int rsel = nl & 3;
    float vr = v[0];
    vr = rsel == 1 ? v[1] : vr;
    vr = rsel == 2 ? v[2] : vr;
    vr = rsel == 3 ? v[3] : vr;
    return vr;
}

// R12: SINGLE dispatch. One molecule (96 atoms) per block: 2048 blocks x
// 384 threads (6 waves, one 16-atom x 64-hid MFMA tile each).
//  - Each block self-builds the W1 frag image in LDS from w1 (32 KB,
//    L2-resident after gen 0; the 1-time prep kernel + its launch boundary
//    and the ws round-trip are gone).
//  - Molecule sum completes in-block (LDS scratch + 2nd barrier) -> plain
//    store to out[mol]: no atomics, no output zeroing anywhere.
//  - rep loads post-barrier (barrier drains only LDS-build traffic),
//    nontemporal (zero reuse; protects L2 for w1).
// LDS frag layout (validated R6/R8, absmax 0.0625): fid=(s*4+t)*64+lane,
// lane elems k=s*32+(lane>>4)*8+j, n=t*16+(lane&15); A m=nl,k=quad*8+j;
// C atom=quad*4+r, hid=nl.
__global__ __launch_bounds__(384, 4) void atomwise_kernel(
    const float* __restrict__ rep,
    const int*   __restrict__ zs,
    const float* __restrict__ mask,
    const float* __restrict__ w1,
    const float* __restrict__ b1,
    const float* __restrict__ w2,
    const float* __restrict__ b2,
    const float* __restrict__ aref,
    const float* __restrict__ mean,
    const float* __restrict__ stddev,
    float* __restrict__ out)
{
    __shared__ unsigned char smem[16928];   // 16384 frag + 256 b1 + 256 w2 + 32 scratch

    const int tid  = threadIdx.x;
    const int lane = tid & 63;
    const int wv   = tid >> 6;          // 0..5: one 16-atom tile per wave
    const int nl   = lane & 15;
    const int quad = lane >> 4;
    const int mol  = blockIdx.x;
    const int atomb = mol * AA + wv * 16;

    // ---- self-build frag image + b1 + w2 in LDS (w1 is L2-resident) ----
    {
        uint4* dst = (uint4*)smem;
        #pragma unroll
        for (int it = 0; it < 3; ++it) {
            const int fid = tid + it * 384;
            if (fid < 1024) {
                const int fl = fid & 63, st = fid >> 6;
                const int s = st >> 2, t = st & 3;
                const int k0 = s * 32 + (fl >> 4) * 8;
                const int n  = t * 16 + (fl & 15);
                const float* wp = w1 + k0 * NHID + n;
                float e[8];
                #pragma unroll
                for (int j = 0; j < 8; ++j) e[j] = wp[j * NHID];
                uint4 v;
                v.x = cvt_pk_hw(e[0], e[1]);
                v.y = cvt_pk_hw(e[2], e[3]);
                v.z = cvt_pk_hw(e[4], e[5]);
                v.w = cvt_pk_hw(e[6], e[7]);
                dst[fid] = v;
            }
        }
        if (tid < 64)       ((float*)(smem + 16384))[tid]      = b1[tid];
        else if (tid < 128) ((float*)(smem + 16640))[tid - 64] = w2[tid - 64];
    }
    __syncthreads();

    // ---- ALL rep HBM traffic post-barrier, nontemporal ----
    const float* rowp = rep + (size_t)(atomb + nl) * NIN + quad * 8;
    f32x4 q[8];
    #pragma unroll
    for (int s = 0; s < 4; ++s) {
        q[2 * s]     = __builtin_nontemporal_load((const f32x4*)(rowp + s * 32));
        q[2 * s + 1] = __builtin_nontemporal_load((const f32x4*)(rowp + s * 32 + 4));
    }

    // epilogue operands (small, independent VM loads behind rep in the queue)
    const int   ag    = atomb + quad * 4 + (nl & 3);
    const float mq    = mask[ag];
    const float arefv = aref[zs[ag]];
    const float sdv   = stddev[0];
    const float cadd  = fmaf(b2[0], sdv, mean[0]);

    const bf16x8* w1f = (const bf16x8*)smem;
    const float*  b1s = (const float*)(smem + 16384);
    const float*  w2s = (const float*)(smem + 16640);
    float b1v[4], w2v[4];
    #pragma unroll
    for (int t = 0; t < 4; ++t) {
        b1v[t] = b1s[t * 16 + nl];
        w2v[t] = w2s[t * 16 + nl];
    }

    f32x4 acc[4];
    #pragma unroll
    for (int t = 0; t < 4; ++t) acc[t] = (f32x4){0.f, 0.f, 0.f, 0.f};

    #pragma unroll
    for (int s = 0; s < 4; ++s) {
        union { bf16x8 v; unsigned u[4]; } fa;
        fa.u[0] = cvt_pk_hw(q[2 * s].x,     q[2 * s].y);
        fa.u[1] = cvt_pk_hw(q[2 * s].z,     q[2 * s].w);
        fa.u[2] = cvt_pk_hw(q[2 * s + 1].x, q[2 * s + 1].y);
        fa.u[3] = cvt_pk_hw(q[2 * s + 1].z, q[2 * s + 1].w);
        const bf16x8* fr = &w1f[s * 256 + lane];
        #pragma unroll
        for (int t = 0; t < 4; ++t)
            acc[t] = __builtin_amdgcn_mfma_f32_16x16x32_bf16(fa.v, fr[t * 64], acc[t], 0, 0, 0);
    }

    const float vr = tile_reduce(acc, b1v, w2v, nl);

    // per-wave sum of its 16 atoms -> scratch[wv]
    float contrib = (nl < 4) ? mq * (fmaf(vr, sdv, cadd) + arefv) : 0.f;
    #pragma unroll
    for (int off = 32; off; off >>= 1) contrib += __shfl_xor(contrib, off);
    float* scratch = (float*)(smem + 16896);
    if (lane == 0) scratch[wv] = contrib;
    __syncthreads();

    // molecule total: plain store (full overwrite of poisoned out; no atomics)
    if (tid == 0) {
        float tot = scratch[0] + scratch[1] + scratch[2]
                  + scratch[3] + scratch[4] + scratch[5];
        out[mol] = tot;
    }
}

extern "C" void kernel_launch(void* const* d_in, const int* in_sizes, int n_in,
                              void* d_out, int out_size, void* d_ws, size_t ws_size,
                              hipStream_t stream) {
    const float* rep    = (const float*)d_in[0];
    const int*   zs     = (const int*)  d_in[1];
    const float* mask   = (const float*)d_in[2];
    const float* w1     = (const float*)d_in[3];
    const float* b1     = (const float*)d_in[4];
    const float* w2     = (const float*)d_in[5];
    const float* b2     = (const float*)d_in[6];
    const float* aref   = (const float*)d_in[7];
    const float* mean   = (const float*)d_in[8];
    const float* stddev = (const float*)d_in[9];
    float* out = (float*)d_out;

    // single dispatch: one molecule per block
    atomwise_kernel<<<dim3(BB), dim3(384), 0, stream>>>(
        rep, zs, mask, w1, b1, w2, b2, aref, mean, stddev, out);
}